// Round 6
// baseline (2218.676 us; speedup 1.0000x reference)
//
#include <hip/hip_runtime.h>
#include <math.h>

#define N_NODES 16384
#define DIM 128
#define HC 384          // HEADS * C
#define NEG_SLOPE 0.2f
#define KNN 16
#define KP 20           // per-segment candidate pool per row
#define KCAP 20         // per-round push buffer capacity
#define NSEG 4
#define NCAND (NSEG * KP)   // 80
#define SEGC (N_NODES / NSEG)

typedef _Float16 f16x8 __attribute__((ext_vector_type(8)));
typedef _Float16 f16x2 __attribute__((ext_vector_type(2)));
typedef float f32x4 __attribute__((ext_vector_type(4)));

__device__ __forceinline__ void barrier_lds() {
  asm volatile("s_waitcnt lgkmcnt(0)" ::: "memory");
  __builtin_amdgcn_s_barrier();
}

// ---------------- prep 1: sq + split x into f16 hi/lo ----------------
__global__ __launch_bounds__(256) void prep_x(const float* __restrict__ x,
                                              float* __restrict__ sq,
                                              _Float16* __restrict__ xhi,
                                              _Float16* __restrict__ xlo) {
  const int wv = threadIdx.x >> 6;
  const int lane = threadIdx.x & 63;
  const int row = blockIdx.x * 4 + wv;
  const float2 v = *(const float2*)&x[row * DIM + lane * 2];
  float s = v.x * v.x + v.y * v.y;
  #pragma unroll
  for (int off = 32; off > 0; off >>= 1) s += __shfl_down(s, off);
  _Float16 h0 = (_Float16)v.x, h1 = (_Float16)v.y;
  _Float16 l0 = (_Float16)(v.x - (float)h0), l1 = (_Float16)(v.y - (float)h1);
  f16x2 hh; hh[0] = h0; hh[1] = h1;
  f16x2 ll; ll[0] = l0; ll[1] = l1;
  *(f16x2*)&xhi[row * DIM + lane * 2] = hh;
  *(f16x2*)&xlo[row * DIM + lane * 2] = ll;
  if (lane == 0) sq[row] = s;
}

// ---------------- prep 2: W transpose + split (WT[c][k]) ----------------
__global__ __launch_bounds__(256) void prep_w(const float* __restrict__ Wl,
                                              const float* __restrict__ Wr,
                                              _Float16* __restrict__ wthi,
                                              _Float16* __restrict__ wtlo) {
  const int t = blockIdx.x * 256 + threadIdx.x;   // [0, 98304)
  const int mat = t / 49152;
  const int e = t - mat * 49152;                  // e = k*384 + c
  const int k = e / HC;
  const int c = e - k * HC;
  const float w = (mat ? Wr : Wl)[e];
  _Float16 h = (_Float16)w;
  _Float16 l = (_Float16)(w - (float)h);
  wthi[mat * 49152 + c * DIM + k] = h;
  wtlo[mat * 49152 + c * DIM + k] = l;
}

// ---------------- xl = x@Wl, xr = x@Wr via MFMA f16-split ----------------
__global__ __launch_bounds__(256) void gemm_xw_mfma(const _Float16* __restrict__ xhi,
                                                    const _Float16* __restrict__ xlo,
                                                    const _Float16* __restrict__ wthi,
                                                    const _Float16* __restrict__ wtlo,
                                                    _Float16* __restrict__ xl,
                                                    _Float16* __restrict__ xr) {
  const int lane = threadIdx.x & 63;
  const int t = blockIdx.x * 4 + (threadIdx.x >> 6);  // [0, 49152)
  const int mat = t / 24576;
  const int rem = t - mat * 24576;
  const int rt = rem / 24;
  const int ct = rem - rt * 24;
  const int r0 = lane & 15;
  const int g8 = (lane >> 4) * 8;
  const _Float16* ap_hi = xhi + (size_t)(rt * 16 + r0) * DIM + g8;
  const _Float16* ap_lo = xlo + (size_t)(rt * 16 + r0) * DIM + g8;
  const _Float16* bp_hi = wthi + mat * 49152 + (ct * 16 + r0) * DIM + g8;
  const _Float16* bp_lo = wtlo + mat * 49152 + (ct * 16 + r0) * DIM + g8;
  f32x4 acc = {0.f, 0.f, 0.f, 0.f};
  #pragma unroll
  for (int ks = 0; ks < 4; ks++) {
    f16x8 ah = *(const f16x8*)(ap_hi + ks * 32);
    f16x8 al = *(const f16x8*)(ap_lo + ks * 32);
    f16x8 bh = *(const f16x8*)(bp_hi + ks * 32);
    f16x8 bl = *(const f16x8*)(bp_lo + ks * 32);
    acc = __builtin_amdgcn_mfma_f32_16x16x32_f16(ah, bh, acc, 0, 0, 0);
    acc = __builtin_amdgcn_mfma_f32_16x16x32_f16(ah, bl, acc, 0, 0, 0);
    acc = __builtin_amdgcn_mfma_f32_16x16x32_f16(al, bh, acc, 0, 0, 0);
  }
  _Float16* o = mat ? xr : xl;
  #pragma unroll
  for (int i = 0; i < 4; i++) {
    const int row = rt * 16 + (lane >> 4) * 4 + i;
    o[(size_t)row * HC + ct * 16 + r0] = (_Float16)acc[i];
  }
}

// ---------------- knn: hi-only MFMA + per-segment top-20 ----------------
// grid (256 row-groups, 4 col-segments), 512 thr. Each block scans 4096 cols
// (16 batches of 256) and emits its segment's top-KP per row.
__global__ __launch_bounds__(512, 2) void knn_kernel(const _Float16* __restrict__ xhi,
                                                     const float* __restrict__ sq,
                                                     int* __restrict__ cand) {
  __shared__ __align__(16) float Thr[64];
  __shared__ int Cnt[64];
  __shared__ float Topd[KP][64];
  __shared__ int   Topi[KP][64];
  __shared__ float Bufd[KCAP][64];
  __shared__ int   Bufi[KCAP][64];
  __shared__ int Flag;

  const int tid = threadIdx.x;
  const int lane = tid & 63;
  const int wv = __builtin_amdgcn_readfirstlane(tid >> 6);
  const int rowbase = blockIdx.x * 64;
  const int seg = blockIdx.y;
  const int segbase = seg * SEGC;
  const int r0 = lane & 15;
  const int g8 = (lane >> 4) * 8;
  const int rb4 = (lane >> 4) * 4;

  // A fragments (hi only): 64 rows of the block in registers
  f16x8 ahi[4][4];
  #pragma unroll
  for (int rt = 0; rt < 4; rt++) {
    const size_t ab = (size_t)(rowbase + rt * 16 + r0) * DIM + g8;
    #pragma unroll
    for (int ks = 0; ks < 4; ks++) ahi[rt][ks] = *(const f16x8*)&xhi[ab + ks * 32];
  }
  f32x4 srv[4];
  #pragma unroll
  for (int rt = 0; rt < 4; rt++) srv[rt] = *(const f32x4*)&sq[rowbase + rt * 16 + rb4];

  if (tid < 64) { Thr[tid] = __builtin_inff(); Cnt[tid] = 0; }
  if (tid == 0) Flag = 0;
  __syncthreads();

  int kcnt = 0, wj = 0, wpos = 0;
  float wd = __builtin_inff();

  const int NB = SEGC / 256;  // 16 batches (2 x 128-col tiles each)
  const int cbase = wv * 16 + r0;

  // preload batch 0
  f16x8 bcur[2][4]; float scur[2];
  #pragma unroll
  for (int tt = 0; tt < 2; tt++) {
    const int cg = segbase + tt * 128 + cbase;
    const size_t bb = (size_t)cg * DIM + g8;
    #pragma unroll
    for (int ks = 0; ks < 4; ks++) bcur[tt][ks] = *(const f16x8*)&xhi[bb + ks * 32];
    scur[tt] = sq[cg];
  }

  for (int b = 0; b < NB; b++) {
    // prefetch batch b+1 (wraps on last iter; unused)
    const int bn = (b + 1 < NB) ? b + 1 : 0;
    f16x8 bnx[2][4]; float snx[2];
    #pragma unroll
    for (int tt = 0; tt < 2; tt++) {
      const int cg = segbase + bn * 256 + tt * 128 + cbase;
      const size_t bb = (size_t)cg * DIM + g8;
      #pragma unroll
      for (int ks = 0; ks < 4; ks++) bnx[tt][ks] = *(const f16x8*)&xhi[bb + ks * 32];
      snx[tt] = sq[cg];
    }

    // MFMA: acc = dot - sc/2
    f32x4 acc[2][4];
    #pragma unroll
    for (int tt = 0; tt < 2; tt++) {
      const float iv = -0.5f * scur[tt];
      #pragma unroll
      for (int rt = 0; rt < 4; rt++) {
        acc[tt][rt][0] = iv; acc[tt][rt][1] = iv; acc[tt][rt][2] = iv; acc[tt][rt][3] = iv;
        #pragma unroll
        for (int ks = 0; ks < 4; ks++)
          acc[tt][rt] = __builtin_amdgcn_mfma_f32_16x16x32_f16(ahi[rt][ks], bcur[tt][ks],
                                                               acc[tt][rt], 0, 0, 0);
      }
    }

    // d = sr - 2*acc (approx); mark non-self
    unsigned pend = 0;
    #pragma unroll
    for (int tt = 0; tt < 2; tt++) {
      const int cg = segbase + b * 256 + tt * 128 + cbase;
      #pragma unroll
      for (int rt = 0; rt < 4; rt++)
        #pragma unroll
        for (int i = 0; i < 4; i++) {
          const int rg = rowbase + rt * 16 + rb4 + i;
          acc[tt][rt][i] = srv[rt][i] - 2.0f * acc[tt][rt][i];
          if (cg != rg) pend |= (1u << (tt * 16 + rt * 4 + i));
        }
    }

    // push/merge rounds (LDS-only sync: raw barrier + lgkmcnt)
    while (true) {
      f32x4 thrv[4];
      #pragma unroll
      for (int rt = 0; rt < 4; rt++) thrv[rt] = *(const f32x4*)&Thr[rt * 16 + rb4];
      #pragma unroll
      for (int tt = 0; tt < 2; tt++)
        #pragma unroll
        for (int rt = 0; rt < 4; rt++)
          #pragma unroll
          for (int i = 0; i < 4; i++) {
            const unsigned bb2 = 1u << (tt * 16 + rt * 4 + i);
            if ((pend & bb2) && !(acc[tt][rt][i] <= thrv[rt][i])) pend &= ~bb2;
          }
      if (tid == 0) Flag = 0;
      barrier_lds();  // B1: reset visible
      if (pend) {
        #pragma unroll
        for (int tt = 0; tt < 2; tt++) {
          const int cg = segbase + b * 256 + tt * 128 + cbase;
          #pragma unroll
          for (int rt = 0; rt < 4; rt++)
            #pragma unroll
            for (int i = 0; i < 4; i++) {
              const unsigned bb2 = 1u << (tt * 16 + rt * 4 + i);
              if (pend & bb2) {
                const int r = rt * 16 + rb4 + i;
                const int slot = atomicAdd(&Cnt[r], 1);
                if (slot < KCAP) {
                  Bufd[slot][r] = acc[tt][rt][i];
                  Bufi[slot][r] = cg;
                  pend &= ~bb2;
                }
              }
            }
        }
        if (pend) Flag = 1;
      }
      barrier_lds();  // B2: pushes + flag visible
      const int fl = Flag;
      if (tid < 64) {
        int nn = Cnt[tid]; if (nn > KCAP) nn = KCAP;
        for (int e = 0; e < nn; e++) {
          const float d = Bufd[e][tid];
          const int jj = Bufi[e][tid];
          bool rescan = false;
          if (kcnt < KP) {
            Topd[kcnt][tid] = d; Topi[kcnt][tid] = jj; kcnt++;
            rescan = (kcnt == KP);
          } else if (d < wd || (d == wd && jj < wj)) {
            Topd[wpos][tid] = d; Topi[wpos][tid] = jj;
            rescan = true;
          }
          if (rescan) {
            wd = Topd[0][tid]; wj = Topi[0][tid]; wpos = 0;
            #pragma unroll
            for (int e2 = 1; e2 < KP; e2++) {
              const float dd = Topd[e2][tid];
              const int j2 = Topi[e2][tid];
              if (dd > wd || (dd == wd && j2 > wj)) { wd = dd; wj = j2; wpos = e2; }
            }
            Thr[tid] = wd;
          }
        }
        Cnt[tid] = 0;
      }
      barrier_lds();  // B3: merge/Thr visible
      if (!fl) break;
    }

    // rotate prefetch
    #pragma unroll
    for (int tt = 0; tt < 2; tt++) {
      #pragma unroll
      for (int ks = 0; ks < 4; ks++) bcur[tt][ks] = bnx[tt][ks];
      scur[tt] = snx[tt];
    }
  }

  if (tid < 64) {
    #pragma unroll
    for (int e = 0; e < KP; e++)
      cand[(size_t)(rowbase + tid) * NCAND + seg * KP + e] = Topi[e][tid];
  }
}

// ---------------- refine: exact f32 re-rank of 80 candidates ----------------
// 512 thr = 4 rows x 128 threads; thread t handles candidate t (<80) of its row.
__global__ __launch_bounds__(512) void refine_kernel(const float* __restrict__ x,
                                                     const float* __restrict__ sq,
                                                     const int* __restrict__ cand,
                                                     int* __restrict__ idxo) {
  __shared__ __align__(16) float Xrow[4][DIM];
  __shared__ float Dall[4][128];
  __shared__ int   Call[4][128];
  const int tid = threadIdx.x;
  const int rr = tid >> 7;
  const int t = tid & 127;
  const int row = blockIdx.x * 4 + rr;
  Xrow[rr][t] = x[(size_t)row * DIM + t];
  __syncthreads();
  float d = __builtin_inff();
  int c = 0x7fffffff;
  if (t < NCAND) {
    c = cand[(size_t)row * NCAND + t];
    const float4* xc4 = (const float4*)&x[(size_t)c * DIM];
    const float4* xr4 = (const float4*)&Xrow[rr][0];
    float dot = 0.f;
    #pragma unroll
    for (int i = 0; i < 32; i++) {
      const float4 a = xr4[i], bb = xc4[i];
      dot += a.x * bb.x + a.y * bb.y + a.z * bb.z + a.w * bb.w;
    }
    d = sq[row] + sq[c] - 2.0f * dot;
  }
  Dall[rr][t] = d; Call[rr][t] = c;
  __syncthreads();
  int rank = 0;
  #pragma unroll 8
  for (int m = 0; m < NCAND; m++) {
    const float dm = Dall[rr][m];
    const int cm = Call[rr][m];
    rank += ((dm < d) || (dm == d && cm < c)) ? 1 : 0;
  }
  if (t < NCAND && rank < KNN) idxo[(size_t)row * KNN + rank] = c;
}

// ---------------- attention epilogue (4 nodes / 256-thr block) ----------------
__global__ __launch_bounds__(256) void attn_kernel(const _Float16* __restrict__ xl,
                                                   const _Float16* __restrict__ xr,
                                                   const float* __restrict__ att,
                                                   const float* __restrict__ bias,
                                                   const int* __restrict__ idxo,
                                                   float* __restrict__ out) {
  const int n = blockIdx.x * 4 + (threadIdx.x >> 6);
  const int lane = threadIdx.x & 63;
  int myn = 0;
  if (lane < KNN) myn = idxo[(size_t)n * KNN + lane];
  float o0 = 0.f, o1 = 0.f;
  #pragma unroll
  for (int h = 0; h < 3; h++) {
    const float r0 = (float)xr[(size_t)n * HC + h * 128 + lane];
    const float r1 = (float)xr[(size_t)n * HC + h * 128 + 64 + lane];
    const float a0 = att[h * 128 + lane];
    const float a1 = att[h * 128 + 64 + lane];
    float v0[KNN], v1[KNN], e[KNN];
    #pragma unroll
    for (int kk = 0; kk < KNN; kk++) {
      const _Float16* xp = &xl[(size_t)__shfl(myn, kk) * HC + h * 128];
      float x0 = (float)xp[lane], x1 = (float)xp[64 + lane];
      v0[kk] = x0; v1[kk] = x1;
      float g0 = x0 + r0; g0 = g0 >= 0.f ? g0 : NEG_SLOPE * g0;
      float g1 = x1 + r1; g1 = g1 >= 0.f ? g1 : NEG_SLOPE * g1;
      float p = a0 * g0 + a1 * g1;
      #pragma unroll
      for (int off = 32; off > 0; off >>= 1) p += __shfl_xor(p, off);
      e[kk] = p;
    }
    float m = e[0];
    #pragma unroll
    for (int kk = 1; kk < KNN; kk++) m = fmaxf(m, e[kk]);
    float s = 0.f;
    float w[KNN];
    #pragma unroll
    for (int kk = 0; kk < KNN; kk++) { w[kk] = expf(e[kk] - m); s += w[kk]; }
    #pragma unroll
    for (int kk = 0; kk < KNN; kk++) {
      float al = w[kk] / s;
      o0 += al * v0[kk];
      o1 += al * v1[kk];
    }
  }
  out[(size_t)n * 128 + lane]      = o0 / 3.f + bias[lane];
  out[(size_t)n * 128 + 64 + lane] = o1 / 3.f + bias[64 + lane];
}

extern "C" void kernel_launch(void* const* d_in, const int* in_sizes, int n_in,
                              void* d_out, int out_size, void* d_ws, size_t ws_size,
                              hipStream_t stream) {
  const float* x    = (const float*)d_in[0];
  const float* Wl   = (const float*)d_in[1];
  const float* Wr   = (const float*)d_in[2];
  const float* att  = (const float*)d_in[3];
  const float* bias = (const float*)d_in[4];
  float* out = (float*)d_out;

  _Float16* xhi  = (_Float16*)d_ws;                    // N*128
  _Float16* xlo  = xhi + (size_t)N_NODES * DIM;        // N*128
  _Float16* wthi = xlo + (size_t)N_NODES * DIM;        // 2*384*128
  _Float16* wtlo = wthi + 2 * HC * DIM;
  _Float16* xl   = wtlo + 2 * HC * DIM;                // N*384
  _Float16* xr   = xl + (size_t)N_NODES * HC;          // N*384
  float*    sqv  = (float*)(xr + (size_t)N_NODES * HC);
  int*      cnd  = (int*)(sqv + N_NODES);              // N*80
  int*      idx  = cnd + (size_t)N_NODES * NCAND;      // N*16

  prep_x<<<N_NODES / 4, 256, 0, stream>>>(x, sqv, xhi, xlo);
  prep_w<<<384, 256, 0, stream>>>(Wl, Wr, wthi, wtlo);
  gemm_xw_mfma<<<12288, 256, 0, stream>>>(xhi, xlo, wthi, wtlo, xl, xr);
  knn_kernel<<<dim3(N_NODES / 64, NSEG), 512, 0, stream>>>(xhi, sqv, cnd);
  refine_kernel<<<N_NODES / 4, 512, 0, stream>>>(x, sqv, cnd, idx);
  attn_kernel<<<N_NODES / 4, 256, 0, stream>>>(xl, xr, att, bias, idx, out);
}

// Round 7
// 2175.920 us; speedup vs baseline: 1.0197x; 1.0197x over previous
//
#include <hip/hip_runtime.h>
#include <math.h>

#define N_NODES 16384
#define DIM 128
#define HC 384          // HEADS * C
#define NEG_SLOPE 0.2f
#define KNN 16
#define KP2 20          // per-lane register pool size
#define NSEG 2
#define NCAND 160       // 4 lane-groups * NSEG * KP2
#define SEGC (N_NODES / NSEG)
#define TILES (SEGC / 16)
#define PAIRS (TILES / 2)

typedef _Float16 f16x8 __attribute__((ext_vector_type(8)));
typedef _Float16 f16x2 __attribute__((ext_vector_type(2)));
typedef float f32x4 __attribute__((ext_vector_type(4)));

// ---------------- prep 1: sq + split x into f16 hi/lo ----------------
__global__ __launch_bounds__(256) void prep_x(const float* __restrict__ x,
                                              float* __restrict__ sq,
                                              _Float16* __restrict__ xhi,
                                              _Float16* __restrict__ xlo) {
  const int wv = threadIdx.x >> 6;
  const int lane = threadIdx.x & 63;
  const int row = blockIdx.x * 4 + wv;
  const float2 v = *(const float2*)&x[row * DIM + lane * 2];
  float s = v.x * v.x + v.y * v.y;
  #pragma unroll
  for (int off = 32; off > 0; off >>= 1) s += __shfl_down(s, off);
  _Float16 h0 = (_Float16)v.x, h1 = (_Float16)v.y;
  _Float16 l0 = (_Float16)(v.x - (float)h0), l1 = (_Float16)(v.y - (float)h1);
  f16x2 hh; hh[0] = h0; hh[1] = h1;
  f16x2 ll; ll[0] = l0; ll[1] = l1;
  *(f16x2*)&xhi[row * DIM + lane * 2] = hh;
  *(f16x2*)&xlo[row * DIM + lane * 2] = ll;
  if (lane == 0) sq[row] = s;
}

// ---------------- prep 2: W transpose + split (WT[c][k]) ----------------
__global__ __launch_bounds__(256) void prep_w(const float* __restrict__ Wl,
                                              const float* __restrict__ Wr,
                                              _Float16* __restrict__ wthi,
                                              _Float16* __restrict__ wtlo) {
  const int t = blockIdx.x * 256 + threadIdx.x;   // [0, 98304)
  const int mat = t / 49152;
  const int e = t - mat * 49152;                  // e = k*384 + c
  const int k = e / HC;
  const int c = e - k * HC;
  const float w = (mat ? Wr : Wl)[e];
  _Float16 h = (_Float16)w;
  _Float16 l = (_Float16)(w - (float)h);
  wthi[mat * 49152 + c * DIM + k] = h;
  wtlo[mat * 49152 + c * DIM + k] = l;
}

// ---------------- xl = x@Wl, xr = x@Wr via MFMA f16-split ----------------
__global__ __launch_bounds__(256) void gemm_xw_mfma(const _Float16* __restrict__ xhi,
                                                    const _Float16* __restrict__ xlo,
                                                    const _Float16* __restrict__ wthi,
                                                    const _Float16* __restrict__ wtlo,
                                                    _Float16* __restrict__ xl,
                                                    _Float16* __restrict__ xr) {
  const int lane = threadIdx.x & 63;
  const int t = blockIdx.x * 4 + (threadIdx.x >> 6);  // [0, 49152)
  const int mat = t / 24576;
  const int rem = t - mat * 24576;
  const int rt = rem / 24;
  const int ct = rem - rt * 24;
  const int r0 = lane & 15;
  const int g8 = (lane >> 4) * 8;
  const _Float16* ap_hi = xhi + (size_t)(rt * 16 + r0) * DIM + g8;
  const _Float16* ap_lo = xlo + (size_t)(rt * 16 + r0) * DIM + g8;
  const _Float16* bp_hi = wthi + mat * 49152 + (ct * 16 + r0) * DIM + g8;
  const _Float16* bp_lo = wtlo + mat * 49152 + (ct * 16 + r0) * DIM + g8;
  f32x4 acc = {0.f, 0.f, 0.f, 0.f};
  #pragma unroll
  for (int ks = 0; ks < 4; ks++) {
    f16x8 ah = *(const f16x8*)(ap_hi + ks * 32);
    f16x8 al = *(const f16x8*)(ap_lo + ks * 32);
    f16x8 bh = *(const f16x8*)(bp_hi + ks * 32);
    f16x8 bl = *(const f16x8*)(bp_lo + ks * 32);
    acc = __builtin_amdgcn_mfma_f32_16x16x32_f16(ah, bh, acc, 0, 0, 0);
    acc = __builtin_amdgcn_mfma_f32_16x16x32_f16(ah, bl, acc, 0, 0, 0);
    acc = __builtin_amdgcn_mfma_f32_16x16x32_f16(al, bh, acc, 0, 0, 0);
  }
  _Float16* o = mat ? xr : xl;
  #pragma unroll
  for (int i = 0; i < 4; i++) {
    const int row = rt * 16 + (lane >> 4) * 4 + i;
    o[(size_t)row * HC + ct * 16 + r0] = (_Float16)acc[i];
  }
}

// ---------------- knn: swapped-operand MFMA + per-lane register top-20 ----------------
// Wave = 16 rows (one per lane&15), scans SEGC cols. mfma(colfeat, rowfeat):
// lane owns row-node (lane&15), col-nodes colbase + (lane>>4)*4 + reg.
// No LDS, no barriers, no atomics.
__device__ __forceinline__ void load_pair(const _Float16* __restrict__ xhi,
                                          int segbase, int pair, int r0, int g8,
                                          f16x8* a) {
  const int cb = segbase + pair * 32;
  const size_t b0 = (size_t)(cb + r0) * DIM + g8;
  const size_t b1 = (size_t)(cb + 16 + r0) * DIM + g8;
  #pragma unroll
  for (int ks = 0; ks < 4; ks++) {
    a[ks] = *(const f16x8*)&xhi[b0 + ks * 32];
    a[4 + ks] = *(const f16x8*)&xhi[b1 + ks * 32];
  }
}

__device__ __forceinline__ void process_tile(const f16x8* a, const f16x8* b,
                                             const float* __restrict__ sq,
                                             int colbase, int rowbase, int r0, int cg4,
                                             float* pd, int* pi) {
  f32x4 acc = {0.f, 0.f, 0.f, 0.f};
  #pragma unroll
  for (int ks = 0; ks < 4; ks++)
    acc = __builtin_amdgcn_mfma_f32_16x16x32_f16(a[ks], b[ks], acc, 0, 0, 0);
  const f32x4 scv = *(const f32x4*)&sq[colbase + cg4];
  #pragma unroll
  for (int r = 0; r < 4; r++) {
    float key = scv[r] - 2.0f * acc[r];     // = d - sr (per-row const sr dropped)
    if (colbase == rowbase && (cg4 + r == r0)) key = __builtin_inff();  // self
    const int cid = colbase + cg4 + r;
    if (key < pd[KP2 - 1]) {
      float cd = key; int ci = cid;
      #pragma unroll
      for (int s = 0; s < KP2; s++) {
        const bool sw = cd < pd[s];
        const float od = sw ? pd[s] : cd;
        const int   oi = sw ? pi[s] : ci;
        pd[s] = sw ? cd : pd[s];
        pi[s] = sw ? ci : pi[s];
        cd = od; ci = oi;
      }
    }
  }
}

__global__ __launch_bounds__(256) void knn_kernel(const _Float16* __restrict__ xhi,
                                                  const float* __restrict__ sq,
                                                  int* __restrict__ cand) {
  const int lane = threadIdx.x & 63;
  const int w = threadIdx.x >> 6;
  const int gw = blockIdx.x * 4 + w;                       // [0, 2048)
  const int rowgroup = __builtin_amdgcn_readfirstlane(gw >> 1);
  const int seg = __builtin_amdgcn_readfirstlane(gw & 1);
  const int rowbase = rowgroup * 16;
  const int segbase = seg * SEGC;
  const int r0 = lane & 15;
  const int g8 = (lane >> 4) * 8;
  const int cg4 = (lane >> 4) * 4;

  // stationary B: this wave's 16 row-features
  f16x8 b[4];
  {
    const size_t rb = (size_t)(rowbase + r0) * DIM + g8;
    #pragma unroll
    for (int ks = 0; ks < 4; ks++) b[ks] = *(const f16x8*)&xhi[rb + ks * 32];
  }

  float pd[KP2]; int pi[KP2];
  #pragma unroll
  for (int j = 0; j < KP2; j++) { pd[j] = __builtin_inff(); pi[j] = 0; }

  f16x8 acur[8], anxt[8];
  load_pair(xhi, segbase, 0, r0, g8, acur);

  for (int p = 0; p < PAIRS; p += 2) {
    load_pair(xhi, segbase, p + 1, r0, g8, anxt);
    process_tile(acur,     b, sq, segbase + p * 32,      rowbase, r0, cg4, pd, pi);
    process_tile(acur + 4, b, sq, segbase + p * 32 + 16, rowbase, r0, cg4, pd, pi);
    load_pair(xhi, segbase, (p + 2) & (PAIRS - 1), r0, g8, acur);
    process_tile(anxt,     b, sq, segbase + p * 32 + 32, rowbase, r0, cg4, pd, pi);
    process_tile(anxt + 4, b, sq, segbase + p * 32 + 48, rowbase, r0, cg4, pd, pi);
  }

  // dump: row = rowbase + r0; slot block = (lanegroup, seg)
  const int row = rowbase + r0;
  int* dst = cand + (size_t)row * NCAND + ((lane >> 4) * NSEG + seg) * KP2;
  #pragma unroll
  for (int e = 0; e < KP2; e++) dst[e] = pi[e];
}

// ---------------- refine: exact f32 re-rank of 160 candidates, 1 row/block ----------------
__global__ __launch_bounds__(256) void refine_kernel(const float* __restrict__ x,
                                                     const float* __restrict__ sq,
                                                     const int* __restrict__ cand,
                                                     int* __restrict__ idxo) {
  __shared__ __align__(16) float Xrow[DIM];
  __shared__ float Dall[NCAND];
  __shared__ int   Call[NCAND];
  const int t = threadIdx.x;
  const int row = blockIdx.x;
  if (t < DIM) Xrow[t] = x[(size_t)row * DIM + t];
  __syncthreads();
  float d = 0.f; int c = 0;
  if (t < NCAND) {
    c = cand[(size_t)row * NCAND + t];
    const float4* xc4 = (const float4*)&x[(size_t)c * DIM];
    const float4* xr4 = (const float4*)&Xrow[0];
    float dot = 0.f;
    #pragma unroll
    for (int i = 0; i < 32; i++) {
      const float4 a = xr4[i], bb = xc4[i];
      dot += a.x * bb.x + a.y * bb.y + a.z * bb.z + a.w * bb.w;
    }
    d = sq[row] + sq[c] - 2.0f * dot;
    Dall[t] = d; Call[t] = c;
  }
  __syncthreads();
  if (t < NCAND) {
    int rank = 0;
    for (int m = 0; m < NCAND; m++) {
      const float dm = Dall[m];
      const int cm = Call[m];
      rank += ((dm < d) || (dm == d && cm < c)) ? 1 : 0;
    }
    if (rank < KNN) idxo[(size_t)row * KNN + rank] = c;
  }
}

// ---------------- attention epilogue (4 nodes / 256-thr block) ----------------
__global__ __launch_bounds__(256) void attn_kernel(const _Float16* __restrict__ xl,
                                                   const _Float16* __restrict__ xr,
                                                   const float* __restrict__ att,
                                                   const float* __restrict__ bias,
                                                   const int* __restrict__ idxo,
                                                   float* __restrict__ out) {
  const int n = blockIdx.x * 4 + (threadIdx.x >> 6);
  const int lane = threadIdx.x & 63;
  int myn = 0;
  if (lane < KNN) myn = idxo[(size_t)n * KNN + lane];
  float o0 = 0.f, o1 = 0.f;
  #pragma unroll
  for (int h = 0; h < 3; h++) {
    const float r0 = (float)xr[(size_t)n * HC + h * 128 + lane];
    const float r1 = (float)xr[(size_t)n * HC + h * 128 + 64 + lane];
    const float a0 = att[h * 128 + lane];
    const float a1 = att[h * 128 + 64 + lane];
    float v0[KNN], v1[KNN], e[KNN];
    #pragma unroll
    for (int kk = 0; kk < KNN; kk++) {
      const _Float16* xp = &xl[(size_t)__shfl(myn, kk) * HC + h * 128];
      float x0 = (float)xp[lane], x1 = (float)xp[64 + lane];
      v0[kk] = x0; v1[kk] = x1;
      float g0 = x0 + r0; g0 = g0 >= 0.f ? g0 : NEG_SLOPE * g0;
      float g1 = x1 + r1; g1 = g1 >= 0.f ? g1 : NEG_SLOPE * g1;
      float p = a0 * g0 + a1 * g1;
      #pragma unroll
      for (int off = 32; off > 0; off >>= 1) p += __shfl_xor(p, off);
      e[kk] = p;
    }
    float m = e[0];
    #pragma unroll
    for (int kk = 1; kk < KNN; kk++) m = fmaxf(m, e[kk]);
    float s = 0.f;
    float w[KNN];
    #pragma unroll
    for (int kk = 0; kk < KNN; kk++) { w[kk] = expf(e[kk] - m); s += w[kk]; }
    #pragma unroll
    for (int kk = 0; kk < KNN; kk++) {
      float al = w[kk] / s;
      o0 += al * v0[kk];
      o1 += al * v1[kk];
    }
  }
  out[(size_t)n * 128 + lane]      = o0 / 3.f + bias[lane];
  out[(size_t)n * 128 + 64 + lane] = o1 / 3.f + bias[64 + lane];
}

extern "C" void kernel_launch(void* const* d_in, const int* in_sizes, int n_in,
                              void* d_out, int out_size, void* d_ws, size_t ws_size,
                              hipStream_t stream) {
  const float* x    = (const float*)d_in[0];
  const float* Wl   = (const float*)d_in[1];
  const float* Wr   = (const float*)d_in[2];
  const float* att  = (const float*)d_in[3];
  const float* bias = (const float*)d_in[4];
  float* out = (float*)d_out;

  _Float16* xhi  = (_Float16*)d_ws;                    // N*128
  _Float16* xlo  = xhi + (size_t)N_NODES * DIM;        // N*128
  _Float16* wthi = xlo + (size_t)N_NODES * DIM;        // 2*384*128
  _Float16* wtlo = wthi + 2 * HC * DIM;
  _Float16* xl   = wtlo + 2 * HC * DIM;                // N*384
  _Float16* xr   = xl + (size_t)N_NODES * HC;          // N*384
  float*    sqv  = (float*)(xr + (size_t)N_NODES * HC);
  int*      cnd  = (int*)(sqv + N_NODES);              // N*160
  int*      idx  = cnd + (size_t)N_NODES * NCAND;      // N*16

  prep_x<<<N_NODES / 4, 256, 0, stream>>>(x, sqv, xhi, xlo);
  prep_w<<<384, 256, 0, stream>>>(Wl, Wr, wthi, wtlo);
  gemm_xw_mfma<<<12288, 256, 0, stream>>>(xhi, xlo, wthi, wtlo, xl, xr);
  knn_kernel<<<N_NODES / 32, 256, 0, stream>>>(xhi, sqv, cnd);
  refine_kernel<<<N_NODES, 256, 0, stream>>>(x, sqv, cnd, idx);
  attn_kernel<<<N_NODES / 4, 256, 0, stream>>>(xl, xr, att, bias, idx, out);
}

// Round 8
// 881.188 us; speedup vs baseline: 2.5178x; 2.4693x over previous
//
#include <hip/hip_runtime.h>
#include <math.h>

#define N_NODES 16384
#define DIM 128
#define HC 384          // HEADS * C
#define NEG_SLOPE 0.2f
#define KNN 16
#define KP2 20          // per-lane register pool size
#define NSEG 2
#define NCAND 160       // 4 lane-groups * NSEG * KP2
#define SEGC (N_NODES / NSEG)
#define TILES (SEGC / 16)   // 512

typedef _Float16 f16x8 __attribute__((ext_vector_type(8)));
typedef _Float16 f16x2 __attribute__((ext_vector_type(2)));
typedef float f32x4 __attribute__((ext_vector_type(4)));

// ---------------- prep 1: sq + split x into f16 hi/lo ----------------
__global__ __launch_bounds__(256) void prep_x(const float* __restrict__ x,
                                              float* __restrict__ sq,
                                              _Float16* __restrict__ xhi,
                                              _Float16* __restrict__ xlo) {
  const int wv = threadIdx.x >> 6;
  const int lane = threadIdx.x & 63;
  const int row = blockIdx.x * 4 + wv;
  const float2 v = *(const float2*)&x[row * DIM + lane * 2];
  float s = v.x * v.x + v.y * v.y;
  #pragma unroll
  for (int off = 32; off > 0; off >>= 1) s += __shfl_down(s, off);
  _Float16 h0 = (_Float16)v.x, h1 = (_Float16)v.y;
  _Float16 l0 = (_Float16)(v.x - (float)h0), l1 = (_Float16)(v.y - (float)h1);
  f16x2 hh; hh[0] = h0; hh[1] = h1;
  f16x2 ll; ll[0] = l0; ll[1] = l1;
  *(f16x2*)&xhi[row * DIM + lane * 2] = hh;
  *(f16x2*)&xlo[row * DIM + lane * 2] = ll;
  if (lane == 0) sq[row] = s;
}

// ---------------- prep 2: W transpose + split (WT[c][k]) ----------------
__global__ __launch_bounds__(256) void prep_w(const float* __restrict__ Wl,
                                              const float* __restrict__ Wr,
                                              _Float16* __restrict__ wthi,
                                              _Float16* __restrict__ wtlo) {
  const int t = blockIdx.x * 256 + threadIdx.x;   // [0, 98304)
  const int mat = t / 49152;
  const int e = t - mat * 49152;                  // e = k*384 + c
  const int k = e / HC;
  const int c = e - k * HC;
  const float w = (mat ? Wr : Wl)[e];
  _Float16 h = (_Float16)w;
  _Float16 l = (_Float16)(w - (float)h);
  wthi[mat * 49152 + c * DIM + k] = h;
  wtlo[mat * 49152 + c * DIM + k] = l;
}

// ---------------- xl = x@Wl, xr = x@Wr via MFMA f16-split ----------------
__global__ __launch_bounds__(256) void gemm_xw_mfma(const _Float16* __restrict__ xhi,
                                                    const _Float16* __restrict__ xlo,
                                                    const _Float16* __restrict__ wthi,
                                                    const _Float16* __restrict__ wtlo,
                                                    _Float16* __restrict__ xl,
                                                    _Float16* __restrict__ xr) {
  const int lane = threadIdx.x & 63;
  const int t = blockIdx.x * 4 + (threadIdx.x >> 6);  // [0, 49152)
  const int mat = t / 24576;
  const int rem = t - mat * 24576;
  const int rt = rem / 24;
  const int ct = rem - rt * 24;
  const int r0 = lane & 15;
  const int g8 = (lane >> 4) * 8;
  const _Float16* ap_hi = xhi + (size_t)(rt * 16 + r0) * DIM + g8;
  const _Float16* ap_lo = xlo + (size_t)(rt * 16 + r0) * DIM + g8;
  const _Float16* bp_hi = wthi + mat * 49152 + (ct * 16 + r0) * DIM + g8;
  const _Float16* bp_lo = wtlo + mat * 49152 + (ct * 16 + r0) * DIM + g8;
  f32x4 acc = {0.f, 0.f, 0.f, 0.f};
  #pragma unroll
  for (int ks = 0; ks < 4; ks++) {
    f16x8 ah = *(const f16x8*)(ap_hi + ks * 32);
    f16x8 al = *(const f16x8*)(ap_lo + ks * 32);
    f16x8 bh = *(const f16x8*)(bp_hi + ks * 32);
    f16x8 bl = *(const f16x8*)(bp_lo + ks * 32);
    acc = __builtin_amdgcn_mfma_f32_16x16x32_f16(ah, bh, acc, 0, 0, 0);
    acc = __builtin_amdgcn_mfma_f32_16x16x32_f16(ah, bl, acc, 0, 0, 0);
    acc = __builtin_amdgcn_mfma_f32_16x16x32_f16(al, bh, acc, 0, 0, 0);
  }
  _Float16* o = mat ? xr : xl;
  #pragma unroll
  for (int i = 0; i < 4; i++) {
    const int row = rt * 16 + (lane >> 4) * 4 + i;
    o[(size_t)row * HC + ct * 16 + r0] = (_Float16)acc[i];
  }
}

// ---------------- knn: swapped-operand MFMA + packed-u32 register top-20 ----------------
__device__ __forceinline__ unsigned umin32(unsigned a, unsigned b) { return a < b ? a : b; }
__device__ __forceinline__ unsigned umax32(unsigned a, unsigned b) { return a > b ? a : b; }

__device__ __forceinline__ void load_tile(const _Float16* __restrict__ xhi,
                                          const float* __restrict__ sq,
                                          int cb, int r0, int g8, int cg4,
                                          f16x8* a, f32x4* sv) {
  const size_t b0 = (size_t)(cb + r0) * DIM + g8;
  #pragma unroll
  for (int ks = 0; ks < 4; ks++) a[ks] = *(const f16x8*)&xhi[b0 + ks * 32];
  *sv = *(const f32x4*)&sq[cb + cg4];
}

__device__ __forceinline__ void insert4(const f32x4 acc, const f32x4 scv,
                                        int cb_cg, int selfid, unsigned* pool) {
  #pragma unroll
  for (int r = 0; r < 4; r++) {
    const int cid = cb_cg + r;
    const float key = fmaf(-2.f, acc[r], scv[r]);  // d - sr (sr const per lane)
    unsigned u = __float_as_uint(key);
    u ^= (unsigned)(((int)u >> 31) | 0x80000000u); // monotone order-preserving flip
    unsigned pk = (u & 0xFFFFC000u) | (unsigned)cid;
    pk = (cid == selfid) ? 0xFFFFFFFFu : pk;       // exclude self
    if (pk < pool[KP2 - 1]) {
      unsigned cur = pk;
      #pragma unroll
      for (int s = 0; s < KP2; s++) {
        const unsigned mn = umin32(cur, pool[s]);
        cur = umax32(cur, pool[s]);
        pool[s] = mn;
      }
    }
  }
}

__global__ __launch_bounds__(256) void knn_kernel(const _Float16* __restrict__ xhi,
                                                  const float* __restrict__ sq,
                                                  int* __restrict__ cand) {
  const int lane = threadIdx.x & 63;
  const int w = threadIdx.x >> 6;
  const int gw = blockIdx.x * 4 + w;                       // [0, 2048)
  const int rowgroup = __builtin_amdgcn_readfirstlane(gw >> 1);
  const int seg = __builtin_amdgcn_readfirstlane(gw & 1);
  const int rowbase = rowgroup * 16;
  const int segbase = seg * SEGC;
  const int r0 = lane & 15;
  const int g8 = (lane >> 4) * 8;
  const int cg4 = (lane >> 4) * 4;
  const int selfid = rowbase + r0;

  // stationary B: this wave's 16 row-features
  f16x8 b[4];
  {
    const size_t rb = (size_t)(rowbase + r0) * DIM + g8;
    #pragma unroll
    for (int ks = 0; ks < 4; ks++) b[ks] = *(const f16x8*)&xhi[rb + ks * 32];
  }

  unsigned pool[KP2];
  #pragma unroll
  for (int j = 0; j < KP2; j++) pool[j] = 0xFFFFFFFFu;

  f16x8 aA[4], aB[4];
  f32x4 sA, sB;
  load_tile(xhi, sq, segbase, r0, g8, cg4, aA, &sA);
  load_tile(xhi, sq, segbase + 16, r0, g8, cg4, aB, &sB);

  for (int t = 0; t < TILES; t += 2) {
    {  // tile t (buffer A)
      f32x4 acc = {0.f, 0.f, 0.f, 0.f};
      #pragma unroll
      for (int ks = 0; ks < 4; ks++)
        acc = __builtin_amdgcn_mfma_f32_16x16x32_f16(aA[ks], b[ks], acc, 0, 0, 0);
      const f32x4 scv = sA;
      const int cb = segbase + t * 16;
      const int tn = (t + 2) & (TILES - 1);
      load_tile(xhi, sq, segbase + tn * 16, r0, g8, cg4, aA, &sA);  // prefetch
      insert4(acc, scv, cb + cg4, selfid, pool);
    }
    {  // tile t+1 (buffer B)
      f32x4 acc = {0.f, 0.f, 0.f, 0.f};
      #pragma unroll
      for (int ks = 0; ks < 4; ks++)
        acc = __builtin_amdgcn_mfma_f32_16x16x32_f16(aB[ks], b[ks], acc, 0, 0, 0);
      const f32x4 scv = sB;
      const int cb = segbase + (t + 1) * 16;
      const int tn = (t + 3) & (TILES - 1);
      load_tile(xhi, sq, segbase + tn * 16, r0, g8, cg4, aB, &sB);  // prefetch
      insert4(acc, scv, cb + cg4, selfid, pool);
    }
  }

  // dump: row = rowbase + r0; slot block = (lanegroup, seg)
  const int row = rowbase + r0;
  int* dst = cand + (size_t)row * NCAND + ((lane >> 4) * NSEG + seg) * KP2;
  #pragma unroll
  for (int e = 0; e < KP2; e++) dst[e] = (int)(pool[e] & 0x3FFFu);
}

// ---------------- refine: exact f32 re-rank of 160 candidates, 1 row/block ----------------
__global__ __launch_bounds__(256) void refine_kernel(const float* __restrict__ x,
                                                     const float* __restrict__ sq,
                                                     const int* __restrict__ cand,
                                                     int* __restrict__ idxo) {
  __shared__ __align__(16) float Xrow[DIM];
  __shared__ float Dall[NCAND];
  __shared__ int   Call[NCAND];
  const int t = threadIdx.x;
  const int row = blockIdx.x;
  if (t < DIM) Xrow[t] = x[(size_t)row * DIM + t];
  __syncthreads();
  float d = 0.f; int c = 0;
  if (t < NCAND) {
    c = cand[(size_t)row * NCAND + t];
    const float4* xc4 = (const float4*)&x[(size_t)c * DIM];
    const float4* xr4 = (const float4*)&Xrow[0];
    float dot = 0.f;
    #pragma unroll
    for (int i = 0; i < 32; i++) {
      const float4 a = xr4[i], bb = xc4[i];
      dot += a.x * bb.x + a.y * bb.y + a.z * bb.z + a.w * bb.w;
    }
    d = sq[row] + sq[c] - 2.0f * dot;
    Dall[t] = d; Call[t] = c;
  }
  __syncthreads();
  if (t < NCAND) {
    int rank = 0;
    for (int m = 0; m < NCAND; m++) {
      const float dm = Dall[m];
      const int cm = Call[m];
      rank += ((dm < d) || (dm == d && cm < c)) ? 1 : 0;
    }
    if (rank < KNN) idxo[(size_t)row * KNN + rank] = c;
  }
}

// ---------------- attention epilogue (4 nodes / 256-thr block) ----------------
__global__ __launch_bounds__(256) void attn_kernel(const _Float16* __restrict__ xl,
                                                   const _Float16* __restrict__ xr,
                                                   const float* __restrict__ att,
                                                   const float* __restrict__ bias,
                                                   const int* __restrict__ idxo,
                                                   float* __restrict__ out) {
  const int n = blockIdx.x * 4 + (threadIdx.x >> 6);
  const int lane = threadIdx.x & 63;
  int myn = 0;
  if (lane < KNN) myn = idxo[(size_t)n * KNN + lane];
  float o0 = 0.f, o1 = 0.f;
  #pragma unroll
  for (int h = 0; h < 3; h++) {
    const float r0 = (float)xr[(size_t)n * HC + h * 128 + lane];
    const float r1 = (float)xr[(size_t)n * HC + h * 128 + 64 + lane];
    const float a0 = att[h * 128 + lane];
    const float a1 = att[h * 128 + 64 + lane];
    float v0[KNN], v1[KNN], e[KNN];
    #pragma unroll
    for (int kk = 0; kk < KNN; kk++) {
      const _Float16* xp = &xl[(size_t)__shfl(myn, kk) * HC + h * 128];
      float x0 = (float)xp[lane], x1 = (float)xp[64 + lane];
      v0[kk] = x0; v1[kk] = x1;
      float g0 = x0 + r0; g0 = g0 >= 0.f ? g0 : NEG_SLOPE * g0;
      float g1 = x1 + r1; g1 = g1 >= 0.f ? g1 : NEG_SLOPE * g1;
      float p = a0 * g0 + a1 * g1;
      #pragma unroll
      for (int off = 32; off > 0; off >>= 1) p += __shfl_xor(p, off);
      e[kk] = p;
    }
    float m = e[0];
    #pragma unroll
    for (int kk = 1; kk < KNN; kk++) m = fmaxf(m, e[kk]);
    float s = 0.f;
    float w[KNN];
    #pragma unroll
    for (int kk = 0; kk < KNN; kk++) { w[kk] = expf(e[kk] - m); s += w[kk]; }
    #pragma unroll
    for (int kk = 0; kk < KNN; kk++) {
      float al = w[kk] / s;
      o0 += al * v0[kk];
      o1 += al * v1[kk];
    }
  }
  out[(size_t)n * 128 + lane]      = o0 / 3.f + bias[lane];
  out[(size_t)n * 128 + 64 + lane] = o1 / 3.f + bias[64 + lane];
}

extern "C" void kernel_launch(void* const* d_in, const int* in_sizes, int n_in,
                              void* d_out, int out_size, void* d_ws, size_t ws_size,
                              hipStream_t stream) {
  const float* x    = (const float*)d_in[0];
  const float* Wl   = (const float*)d_in[1];
  const float* Wr   = (const float*)d_in[2];
  const float* att  = (const float*)d_in[3];
  const float* bias = (const float*)d_in[4];
  float* out = (float*)d_out;

  _Float16* xhi  = (_Float16*)d_ws;                    // N*128
  _Float16* xlo  = xhi + (size_t)N_NODES * DIM;        // N*128
  _Float16* wthi = xlo + (size_t)N_NODES * DIM;        // 2*384*128
  _Float16* wtlo = wthi + 2 * HC * DIM;
  _Float16* xl   = wtlo + 2 * HC * DIM;                // N*384
  _Float16* xr   = xl + (size_t)N_NODES * HC;          // N*384
  float*    sqv  = (float*)(xr + (size_t)N_NODES * HC);
  int*      cnd  = (int*)(sqv + N_NODES);              // N*160
  int*      idx  = cnd + (size_t)N_NODES * NCAND;      // N*16

  prep_x<<<N_NODES / 4, 256, 0, stream>>>(x, sqv, xhi, xlo);
  prep_w<<<384, 256, 0, stream>>>(Wl, Wr, wthi, wtlo);
  gemm_xw_mfma<<<12288, 256, 0, stream>>>(xhi, xlo, wthi, wtlo, xl, xr);
  knn_kernel<<<N_NODES / 32, 256, 0, stream>>>(xhi, sqv, cnd);
  refine_kernel<<<N_NODES, 256, 0, stream>>>(x, sqv, cnd, idx);
  attn_kernel<<<N_NODES / 4, 256, 0, stream>>>(xl, xr, att, bias, idx, out);
}